// Round 2
// baseline (8275.378 us; speedup 1.0000x reference)
//
#include <hip/hip_runtime.h>

#define B_  8
#define N_  2048
#define H_  1024
#define FF_ 4096
#define M1  8      // rows per block, attention kernel
#define M2  8      // rows per block, FFN kernel
constexpr float EPS_ = 1e-5f;

// Cross-block per-row reduction over NW waves: each thread contributes v[r];
// result broadcast to all. red must be __shared__ float[NW*R].
template<bool IS_MAX, int R, int NW>
__device__ __forceinline__ void block_row_reduce(float (&v)[R], float* red, int t) {
  const int lane = t & 63;
  const int wave = t >> 6;
#pragma unroll
  for (int r = 0; r < R; ++r) {
    float x = v[r];
#pragma unroll
    for (int off = 32; off > 0; off >>= 1) {
      float o = __shfl_xor(x, off, 64);
      x = IS_MAX ? fmaxf(x, o) : (x + o);
    }
    if (lane == 0) red[wave * R + r] = x;
  }
  __syncthreads();
#pragma unroll
  for (int r = 0; r < R; ++r) {
    float acc = red[r];
#pragma unroll
    for (int w = 1; w < NW; ++w) {
      float o = red[w * R + r];
      acc = IS_MAX ? fmaxf(acc, o) : (acc + o);
    }
    v[r] = acc;
  }
  __syncthreads();
}

// Kernel 1: attended = softmax(x x^T) x ; h = LN1(x + attended) -> hout (= d_out)
// Block: 256 threads, owns M1=8 rows of one batch.
// Score ownership: thread t owns j in {4t..4t+3} and {1024+4t..1024+4t+3}.
// QK staging: k-chunks of 8 into sbuf[kk][2048] with XOR-swizzled rows
// (word = kk*2048 + (row ^ (kk & ~3)), an involution since key bits>=2).
__global__ __launch_bounds__(256, 2)
void attn_ln1_kernel(const float* __restrict__ x,
                     const float* __restrict__ ln1g,
                     const float* __restrict__ ln1b,
                     float* __restrict__ hout) {
  __shared__ float sbuf[8 * N_];   // 64 KiB: QK k-chunk staging, later P [i][j]
  __shared__ float qbuf[M1 * 8];   // this block's own rows, current k-chunk
  __shared__ float red[4 * M1];
  const int t  = threadIdx.x;
  const int b  = blockIdx.y;
  const int m0 = blockIdx.x * M1;
  const float* __restrict__ xb = x + (size_t)b * N_ * H_;

  float s[M1][8];
#pragma unroll
  for (int i = 0; i < M1; ++i)
#pragma unroll
    for (int c = 0; c < 8; ++c) s[i][c] = 0.f;

  const int rr = t >> 1;       // staging: 2 lanes per row (32B global runs)
  const int q2 = t & 1;        // which float4 of the 8-float k-slice
  const int wkey = 4 * q2;     // write swizzle key = (kk & ~3)

  // ---- scores over H in k-chunks of 8 ----
  for (int k0 = 0; k0 < H_; k0 += 8) {
    __syncthreads();           // prior compute done reading sbuf
#pragma unroll
    for (int it = 0; it < 16; ++it) {
      const int row = it * 128 + rr;                    // 0..2047
      const float4 v = *(const float4*)(xb + (size_t)row * H_ + k0 + 4 * q2);
      const int wb = wkey * 2048 + (row ^ wkey);
      sbuf[wb + 0 * 2048] = v.x;
      sbuf[wb + 1 * 2048] = v.y;
      sbuf[wb + 2 * 2048] = v.z;
      sbuf[wb + 3 * 2048] = v.w;
      if ((unsigned)(row - m0) < 8u) {                  // duplicate own rows
        const int qi = row - m0;
        qbuf[qi * 8 + 4 * q2 + 0] = v.x;
        qbuf[qi * 8 + 4 * q2 + 1] = v.y;
        qbuf[qi * 8 + 4 * q2 + 2] = v.z;
        qbuf[qi * 8 + 4 * q2 + 3] = v.w;
      }
    }
    __syncthreads();
#pragma unroll
    for (int ks = 0; ks < 2; ++ks) {
      float4 rv[M1];
#pragma unroll
      for (int i = 0; i < M1; ++i) rv[i] = *(const float4*)&qbuf[i * 8 + 4 * ks];
      const int cb = (4 * t) ^ (4 * ks);
#pragma unroll
      for (int e = 0; e < 4; ++e) {
        const float4 c0 = *(const float4*)&sbuf[(4 * ks + e) * 2048 + cb];
        const float4 c1 = *(const float4*)&sbuf[(4 * ks + e) * 2048 + 1024 + cb];
#pragma unroll
        for (int i = 0; i < M1; ++i) {
          const float a = (e == 0) ? rv[i].x : (e == 1) ? rv[i].y
                        : (e == 2) ? rv[i].z : rv[i].w;
          s[i][0] = fmaf(a, c0.x, s[i][0]);
          s[i][1] = fmaf(a, c0.y, s[i][1]);
          s[i][2] = fmaf(a, c0.z, s[i][2]);
          s[i][3] = fmaf(a, c0.w, s[i][3]);
          s[i][4] = fmaf(a, c1.x, s[i][4]);
          s[i][5] = fmaf(a, c1.y, s[i][5]);
          s[i][6] = fmaf(a, c1.z, s[i][6]);
          s[i][7] = fmaf(a, c1.w, s[i][7]);
        }
      }
    }
  }

  // ---- softmax over full row ----
  float m[M1];
#pragma unroll
  for (int i = 0; i < M1; ++i) {
    float lm = s[i][0];
#pragma unroll
    for (int c = 1; c < 8; ++c) lm = fmaxf(lm, s[i][c]);
    m[i] = lm;
  }
  block_row_reduce<true, M1, 4>(m, red, t);   // syncs cover last sbuf reads

  float l[M1];
#pragma unroll
  for (int i = 0; i < M1; ++i) {
    float ls = 0.f;
#pragma unroll
    for (int c = 0; c < 8; ++c) {
      s[i][c] = __expf(s[i][c] - m[i]);
      ls += s[i][c];
    }
    l[i] = ls;
  }
  block_row_reduce<false, M1, 4>(l, red, t);

  // ---- store unnormalized P as [i][j] (float4, no swizzle; PV reads bcast) ----
#pragma unroll
  for (int i = 0; i < M1; ++i) {
    float4 p0 = {s[i][0], s[i][1], s[i][2], s[i][3]};
    float4 p1 = {s[i][4], s[i][5], s[i][6], s[i][7]};
    *(float4*)&sbuf[i * 2048 + 4 * t]        = p0;
    *(float4*)&sbuf[i * 2048 + 1024 + 4 * t] = p1;
  }
  __syncthreads();

  // ---- PV: thread owns h-columns 4t..4t+3 ----
  float acc[M1][4];
#pragma unroll
  for (int i = 0; i < M1; ++i)
#pragma unroll
    for (int c = 0; c < 4; ++c) acc[i][c] = 0.f;

  for (int j = 0; j < N_; j += 4) {
    float4 xv0 = *(const float4*)(xb + (size_t)(j + 0) * H_ + 4 * t);
    float4 xv1 = *(const float4*)(xb + (size_t)(j + 1) * H_ + 4 * t);
    float4 xv2 = *(const float4*)(xb + (size_t)(j + 2) * H_ + 4 * t);
    float4 xv3 = *(const float4*)(xb + (size_t)(j + 3) * H_ + 4 * t);
#pragma unroll
    for (int i = 0; i < M1; ++i) {
      const float4 p = *(const float4*)&sbuf[i * 2048 + j];
      acc[i][0] = fmaf(p.x, xv0.x, acc[i][0]);
      acc[i][1] = fmaf(p.x, xv0.y, acc[i][1]);
      acc[i][2] = fmaf(p.x, xv0.z, acc[i][2]);
      acc[i][3] = fmaf(p.x, xv0.w, acc[i][3]);
      acc[i][0] = fmaf(p.y, xv1.x, acc[i][0]);
      acc[i][1] = fmaf(p.y, xv1.y, acc[i][1]);
      acc[i][2] = fmaf(p.y, xv1.z, acc[i][2]);
      acc[i][3] = fmaf(p.y, xv1.w, acc[i][3]);
      acc[i][0] = fmaf(p.z, xv2.x, acc[i][0]);
      acc[i][1] = fmaf(p.z, xv2.y, acc[i][1]);
      acc[i][2] = fmaf(p.z, xv2.z, acc[i][2]);
      acc[i][3] = fmaf(p.z, xv2.w, acc[i][3]);
      acc[i][0] = fmaf(p.w, xv3.x, acc[i][0]);
      acc[i][1] = fmaf(p.w, xv3.y, acc[i][1]);
      acc[i][2] = fmaf(p.w, xv3.z, acc[i][2]);
      acc[i][3] = fmaf(p.w, xv3.w, acc[i][3]);
    }
  }

  // ---- y = x + attended/l ; LN1 ; write h ----
  const float4 gv = *(const float4*)(ln1g + 4 * t);
  const float4 bv = *(const float4*)(ln1b + 4 * t);
  float y[M1][4];
  float mu[M1];
#pragma unroll
  for (int i = 0; i < M1; ++i) {
    const float li = 1.0f / l[i];
    float4 xv = *(const float4*)(xb + (size_t)(m0 + i) * H_ + 4 * t);
    y[i][0] = fmaf(acc[i][0], li, xv.x);
    y[i][1] = fmaf(acc[i][1], li, xv.y);
    y[i][2] = fmaf(acc[i][2], li, xv.z);
    y[i][3] = fmaf(acc[i][3], li, xv.w);
    mu[i] = (y[i][0] + y[i][1]) + (y[i][2] + y[i][3]);
  }
  block_row_reduce<false, M1, 4>(mu, red, t);
  float var[M1];
#pragma unroll
  for (int i = 0; i < M1; ++i) {
    mu[i] *= (1.0f / H_);
    float q = 0.f;
#pragma unroll
    for (int c = 0; c < 4; ++c) {
      const float d = y[i][c] - mu[i];
      q = fmaf(d, d, q);
    }
    var[i] = q;
  }
  block_row_reduce<false, M1, 4>(var, red, t);
#pragma unroll
  for (int i = 0; i < M1; ++i) {
    const float rs = rsqrtf(var[i] * (1.0f / H_) + EPS_);
    float4 o;
    o.x = fmaf((y[i][0] - mu[i]) * rs, gv.x, bv.x);
    o.y = fmaf((y[i][1] - mu[i]) * rs, gv.y, bv.y);
    o.z = fmaf((y[i][2] - mu[i]) * rs, gv.z, bv.z);
    o.w = fmaf((y[i][3] - mu[i]) * rs, gv.w, bv.w);
    *(float4*)(hout + (size_t)b * N_ * H_ + (size_t)(m0 + i) * H_ + 4 * t) = o;
  }
}

// Kernel 2: out = LN2(h + GELU(h w1 + b1) w2 + b2), in place on hio (= d_out).
// Weights read DIRECTLY from global (coalesced float4, each element used by
// exactly one thread per block -> LDS staging bought nothing). LDS holds only
// broadcast-shared data: h rows + GELU(u) tile. 9 barriers total (was ~1030).
__global__ __launch_bounds__(256, 2)
void ffn_ln2_kernel(float* __restrict__ hio,
                    const float* __restrict__ ln2g,
                    const float* __restrict__ ln2b,
                    const float* __restrict__ w1,
                    const float* __restrict__ bb1,
                    const float* __restrict__ w2,
                    const float* __restrict__ bb2) {
  __shared__ float hlds[M2 * H_];   // 32 KiB: block's h rows
  __shared__ float gbuf[M2 * 1024]; // 32 KiB: gelu(u) per f-tile
  __shared__ float red[4 * M2];
  const int t  = threadIdx.x;
  const int b  = blockIdx.y;
  const int m0 = blockIdx.x * M2;
  float* __restrict__ hb = hio + (size_t)b * N_ * H_ + (size_t)m0 * H_;

  // stage h rows (coalesced)
#pragma unroll
  for (int it = 0; it < 8; ++it) {
    const int fi  = it * 256 + t;       // 2048 float4s total
    const int row = fi >> 8, c4 = fi & 255;
    *(float4*)&hlds[row * H_ + c4 * 4] = *(const float4*)(hb + (size_t)row * H_ + c4 * 4);
  }
  __syncthreads();

  float accO[M2][4];
#pragma unroll
  for (int i = 0; i < M2; ++i)
#pragma unroll
    for (int c = 0; c < 4; ++c) accO[i][c] = 0.f;

  for (int f0 = 0; f0 < FF_; f0 += 1024) {
    // ---- u = h @ w1[:, f0+4t..4t+3]; w1 from global, h broadcast from LDS ----
    float u[M2][4];
#pragma unroll
    for (int i = 0; i < M2; ++i)
#pragma unroll
      for (int c = 0; c < 4; ++c) u[i][c] = 0.f;

    for (int k0 = 0; k0 < H_; k0 += 8) {
      float4 wv[8];
#pragma unroll
      for (int kk = 0; kk < 8; ++kk)
        wv[kk] = *(const float4*)(w1 + (size_t)(k0 + kk) * FF_ + f0 + 4 * t);
#pragma unroll
      for (int i = 0; i < M2; ++i) {
        const float4 ha = *(const float4*)&hlds[i * H_ + k0];
        const float4 hc = *(const float4*)&hlds[i * H_ + k0 + 4];
#pragma unroll
        for (int c = 0; c < 4; ++c) {
          const float w0 = (c==0)?wv[0].x:(c==1)?wv[0].y:(c==2)?wv[0].z:wv[0].w;
          const float w1v= (c==0)?wv[1].x:(c==1)?wv[1].y:(c==2)?wv[1].z:wv[1].w;
          const float w2v= (c==0)?wv[2].x:(c==1)?wv[2].y:(c==2)?wv[2].z:wv[2].w;
          const float w3v= (c==0)?wv[3].x:(c==1)?wv[3].y:(c==2)?wv[3].z:wv[3].w;
          const float w4v= (c==0)?wv[4].x:(c==1)?wv[4].y:(c==2)?wv[4].z:wv[4].w;
          const float w5v= (c==0)?wv[5].x:(c==1)?wv[5].y:(c==2)?wv[5].z:wv[5].w;
          const float w6v= (c==0)?wv[6].x:(c==1)?wv[6].y:(c==2)?wv[6].z:wv[6].w;
          const float w7v= (c==0)?wv[7].x:(c==1)?wv[7].y:(c==2)?wv[7].z:wv[7].w;
          u[i][c] = fmaf(ha.x, w0,  u[i][c]);
          u[i][c] = fmaf(ha.y, w1v, u[i][c]);
          u[i][c] = fmaf(ha.z, w2v, u[i][c]);
          u[i][c] = fmaf(ha.w, w3v, u[i][c]);
          u[i][c] = fmaf(hc.x, w4v, u[i][c]);
          u[i][c] = fmaf(hc.y, w5v, u[i][c]);
          u[i][c] = fmaf(hc.z, w6v, u[i][c]);
          u[i][c] = fmaf(hc.w, w7v, u[i][c]);
        }
      }
    }

    // ---- bias + exact GELU -> gbuf ----
    __syncthreads();   // previous tile's mm2 readers of gbuf are done
    {
      const float4 b1v = *(const float4*)(bb1 + f0 + 4 * t);
#pragma unroll
      for (int i = 0; i < M2; ++i) {
        float4 g;
        const float u0 = u[i][0] + b1v.x;
        const float u1 = u[i][1] + b1v.y;
        const float u2 = u[i][2] + b1v.z;
        const float u3 = u[i][3] + b1v.w;
        g.x = 0.5f * u0 * (1.0f + erff(u0 * 0.70710678118654752f));
        g.y = 0.5f * u1 * (1.0f + erff(u1 * 0.70710678118654752f));
        g.z = 0.5f * u2 * (1.0f + erff(u2 * 0.70710678118654752f));
        g.w = 0.5f * u3 * (1.0f + erff(u3 * 0.70710678118654752f));
        *(float4*)&gbuf[i * 1024 + 4 * t] = g;
      }
    }
    __syncthreads();

    // ---- accO += gelu(u) @ w2[f0:f0+1024, 4t..4t+3]; w2 from global ----
    for (int f = 0; f < 1024; f += 4) {
      float4 wv2[4];
#pragma unroll
      for (int ff = 0; ff < 4; ++ff)
        wv2[ff] = *(const float4*)(w2 + (size_t)(f0 + f + ff) * H_ + 4 * t);
#pragma unroll
      for (int i = 0; i < M2; ++i) {
        const float4 g = *(const float4*)&gbuf[i * 1024 + f];
        accO[i][0] = fmaf(g.x, wv2[0].x, accO[i][0]);
        accO[i][1] = fmaf(g.x, wv2[0].y, accO[i][1]);
        accO[i][2] = fmaf(g.x, wv2[0].z, accO[i][2]);
        accO[i][3] = fmaf(g.x, wv2[0].w, accO[i][3]);
        accO[i][0] = fmaf(g.y, wv2[1].x, accO[i][0]);
        accO[i][1] = fmaf(g.y, wv2[1].y, accO[i][1]);
        accO[i][2] = fmaf(g.y, wv2[1].z, accO[i][2]);
        accO[i][3] = fmaf(g.y, wv2[1].w, accO[i][3]);
        accO[i][0] = fmaf(g.z, wv2[2].x, accO[i][0]);
        accO[i][1] = fmaf(g.z, wv2[2].y, accO[i][1]);
        accO[i][2] = fmaf(g.z, wv2[2].z, accO[i][2]);
        accO[i][3] = fmaf(g.z, wv2[2].w, accO[i][3]);
        accO[i][0] = fmaf(g.w, wv2[3].x, accO[i][0]);
        accO[i][1] = fmaf(g.w, wv2[3].y, accO[i][1]);
        accO[i][2] = fmaf(g.w, wv2[3].z, accO[i][2]);
        accO[i][3] = fmaf(g.w, wv2[3].w, accO[i][3]);
      }
    }
    __syncthreads();   // gbuf readers done before next tile overwrites
  }

  // ---- y = h + ffn + b2 ; LN2 ; write out (in place) ----
  const float4 b2v = *(const float4*)(bb2 + 4 * t);
  const float4 gv  = *(const float4*)(ln2g + 4 * t);
  const float4 bv  = *(const float4*)(ln2b + 4 * t);
  float y[M2][4];
  float mu[M2];
#pragma unroll
  for (int i = 0; i < M2; ++i) {
    y[i][0] = hlds[i * H_ + 4 * t + 0] + accO[i][0] + b2v.x;
    y[i][1] = hlds[i * H_ + 4 * t + 1] + accO[i][1] + b2v.y;
    y[i][2] = hlds[i * H_ + 4 * t + 2] + accO[i][2] + b2v.z;
    y[i][3] = hlds[i * H_ + 4 * t + 3] + accO[i][3] + b2v.w;
    mu[i] = (y[i][0] + y[i][1]) + (y[i][2] + y[i][3]);
  }
  block_row_reduce<false, M2, 4>(mu, red, t);
  float var[M2];
#pragma unroll
  for (int i = 0; i < M2; ++i) {
    mu[i] *= (1.0f / H_);
    float q = 0.f;
#pragma unroll
    for (int c = 0; c < 4; ++c) {
      const float d = y[i][c] - mu[i];
      q = fmaf(d, d, q);
    }
    var[i] = q;
  }
  block_row_reduce<false, M2, 4>(var, red, t);
#pragma unroll
  for (int i = 0; i < M2; ++i) {
    const float rs = rsqrtf(var[i] * (1.0f / H_) + EPS_);
    float4 o;
    o.x = fmaf((y[i][0] - mu[i]) * rs, gv.x, bv.x);
    o.y = fmaf((y[i][1] - mu[i]) * rs, gv.y, bv.y);
    o.z = fmaf((y[i][2] - mu[i]) * rs, gv.z, bv.z);
    o.w = fmaf((y[i][3] - mu[i]) * rs, gv.w, bv.w);
    *(float4*)(hb + (size_t)i * H_ + 4 * t) = o;
  }
}

extern "C" void kernel_launch(void* const* d_in, const int* in_sizes, int n_in,
                              void* d_out, int out_size, void* d_ws, size_t ws_size,
                              hipStream_t stream) {
  (void)in_sizes; (void)n_in; (void)out_size; (void)d_ws; (void)ws_size;
  const float* x    = (const float*)d_in[0];
  const float* ln1g = (const float*)d_in[1];
  const float* ln1b = (const float*)d_in[2];
  const float* ln2g = (const float*)d_in[3];
  const float* ln2b = (const float*)d_in[4];
  const float* w1   = (const float*)d_in[5];
  const float* bb1  = (const float*)d_in[6];
  const float* w2   = (const float*)d_in[7];
  const float* bb2  = (const float*)d_in[8];
  float* out = (float*)d_out;

  dim3 grid(N_ / M1, B_);
  attn_ln1_kernel<<<grid, 256, 0, stream>>>(x, ln1g, ln1b, out);
  dim3 grid2(N_ / M2, B_);
  ffn_ln2_kernel<<<grid2, 256, 0, stream>>>(out, ln2g, ln2b, w1, bb1, w2, bb2);
}

// Round 3
// 2040.476 us; speedup vs baseline: 4.0556x; 4.0556x over previous
//
#include <hip/hip_runtime.h>
#include <stdint.h>

#define NB 8
#define NN 2048
#define HH 1024
#define FFD 4096
constexpr float EPS_ = 1e-5f;

typedef _Float16 f16;
typedef _Float16 f16x8 __attribute__((ext_vector_type(8)));
typedef float f32x4 __attribute__((ext_vector_type(4)));

__device__ __forceinline__ f32x4 MFMA(f16x8 a, f16x8 b, f32x4 c) {
  return __builtin_amdgcn_mfma_f32_16x16x32_f16(a, b, c, 0, 0, 0);
}
__device__ __forceinline__ ushort h2u(f16 h) { union { f16 h; ushort u; } v; v.h = h; return v.u; }
__device__ __forceinline__ uint pack2(float a, float b) {
  return (uint)h2u((f16)a) | ((uint)h2u((f16)b) << 16);
}
__device__ __forceinline__ float4 ld4(const float* p) { return *(const float4*)p; }
__device__ __forceinline__ float gelu(float u) {
  return 0.5f * u * (1.0f + erff(u * 0.70710678118654752f));
}

// ---------------- prep: transpose fp32 -> f16   dst[C][R] = (f16)src[R][C] ----------------
__global__ void transpose_f16(const float* __restrict__ src, f16* __restrict__ dst,
                              int R, int C) {
  __shared__ float tl[32][33];
  const int t = threadIdx.x;
  const int c0 = blockIdx.x * 32, r0 = blockIdx.y * 32;
  {
    const int r = t >> 3, c4 = t & 7;
    float4 v = ld4(src + (size_t)(r0 + r) * C + c0 + c4 * 4);
    tl[r][c4 * 4 + 0] = v.x; tl[r][c4 * 4 + 1] = v.y;
    tl[r][c4 * 4 + 2] = v.z; tl[r][c4 * 4 + 3] = v.w;
  }
  __syncthreads();
  {
    const int c = t >> 3, r4 = t & 7;
    ushort4 o;
    o.x = h2u((f16)tl[r4 * 4 + 0][c]);
    o.y = h2u((f16)tl[r4 * 4 + 1][c]);
    o.z = h2u((f16)tl[r4 * 4 + 2][c]);
    o.w = h2u((f16)tl[r4 * 4 + 3][c]);
    *(ushort4*)(dst + (size_t)(c0 + c) * R + r0 + r4 * 4) = o;
  }
}

// ---------------- attn: h = LN1(x + softmax(x x^T) x), flash, f16 MFMA ----------------
// 1024 thr (16 waves), BM=32 rows/block, BN=256 col tiles, online softmax.
// QK: x3 hi/lo split.  PV: P,V single f16.
// LDS: AB q[2][32][80] | BB cols[2][256][80] | PB P[32][528] | VB V[1024][80] | RD/RD2
__global__ __launch_bounds__(1024)
void attn_kernel(const float* __restrict__ x, const float* __restrict__ g1,
                 const float* __restrict__ lb1, float* __restrict__ hout) {
  extern __shared__ char smem[];
  char* AB = smem;                 // 5120
  char* BB = smem + 5120;          // 40960
  char* PB = smem + 46080;         // 16896
  char* VB = smem + 62976;         // 81920
  float* RD  = (float*)(smem + 144896);
  float* RD2 = (float*)(smem + 145920);

  const int t = threadIdx.x, l = t & 63, w = t >> 6;
  const int lg = l >> 4, li = l & 15;
  const int wr = w >> 3, wc = w & 7;
  const int b = blockIdx.y, m0 = blockIdx.x * 32;
  const float* __restrict__ xb = x + (size_t)b * NN * HH;

  // staging thread maps
  const int ar = t >> 5, ak = t & 31;       // abuf: 32r x 32k
  const int bj = t >> 2, bq = t & 3;        // bbuf: 256j x (4 x 8k)
  const int vjp = t & 15, vhg = t >> 4;     // vbuf: j-pairs 16, h-groups 64x16

  f32x4 Oacc[8] = {};                        // rows wr*16+lg*4+r, cols wc*128+ti*16+li
  float m_run[4] = {-INFINITY, -INFINITY, -INFINITY, -INFINITY};
  float l_run[4] = {0.f, 0.f, 0.f, 0.f};

  for (int jt = 0; jt < 8; ++jt) {
    const int j0 = jt * 256;
    f32x4 sacc[2] = {};
    // ---- QK over k-chunks of 32, register-prefetched staging ----
    float qv = xb[(size_t)(m0 + ar) * HH + ak];
    float4 ca = ld4(xb + (size_t)(j0 + bj) * HH + bq * 8);
    float4 cb = ld4(xb + (size_t)(j0 + bj) * HH + bq * 8 + 4);
    for (int kc = 0; kc < 32; ++kc) {
      __syncthreads();
      { // write LDS (hi/lo split)
        f16 qh = (f16)qv; f16 ql = (f16)(qv - (float)qh);
        *(ushort*)(AB + ar * 80 + ak * 2) = h2u(qh);
        *(ushort*)(AB + 2560 + ar * 80 + ak * 2) = h2u(ql);
        float vv[8] = {ca.x, ca.y, ca.z, ca.w, cb.x, cb.y, cb.z, cb.w};
        f16x8 hi8, lo8;
#pragma unroll
        for (int i = 0; i < 8; ++i) {
          f16 h = (f16)vv[i]; hi8[i] = h; lo8[i] = (f16)(vv[i] - (float)h);
        }
        *(f16x8*)(BB + bj * 80 + bq * 16) = hi8;
        *(f16x8*)(BB + 20480 + bj * 80 + bq * 16) = lo8;
      }
      if (kc < 31) { // prefetch next chunk
        const int k0 = (kc + 1) * 32;
        qv = xb[(size_t)(m0 + ar) * HH + k0 + ak];
        ca = ld4(xb + (size_t)(j0 + bj) * HH + k0 + bq * 8);
        cb = ld4(xb + (size_t)(j0 + bj) * HH + k0 + bq * 8 + 4);
      }
      __syncthreads();
      const int arow = wr * 16 + li;
      f16x8 ahi = *(const f16x8*)(AB + arow * 80 + lg * 16);
      f16x8 alo = *(const f16x8*)(AB + 2560 + arow * 80 + lg * 16);
#pragma unroll
      for (int ct = 0; ct < 2; ++ct) {
        const int j = wc * 32 + ct * 16 + li;
        f16x8 bhi = *(const f16x8*)(BB + j * 80 + lg * 16);
        f16x8 blo = *(const f16x8*)(BB + 20480 + j * 80 + lg * 16);
        sacc[ct] = MFMA(ahi, bhi, sacc[ct]);
        sacc[ct] = MFMA(ahi, blo, sacc[ct]);
        sacc[ct] = MFMA(alo, bhi, sacc[ct]);
      }
    }

    // ---- online softmax for this tile ----
    float tm[4];
#pragma unroll
    for (int r = 0; r < 4; ++r) tm[r] = fmaxf(sacc[0][r], sacc[1][r]);
#pragma unroll
    for (int off = 1; off <= 8; off <<= 1)
#pragma unroll
      for (int r = 0; r < 4; ++r) tm[r] = fmaxf(tm[r], __shfl_xor(tm[r], off, 64));
    if (li == 0)
#pragma unroll
      for (int r = 0; r < 4; ++r) RD[wc * 32 + wr * 16 + lg * 4 + r] = tm[r];
    __syncthreads();
    float mnew[4], fct[4];
#pragma unroll
    for (int r = 0; r < 4; ++r) {
      const int row = wr * 16 + lg * 4 + r;
      float mt = RD[row];
#pragma unroll
      for (int w2 = 1; w2 < 8; ++w2) mt = fmaxf(mt, RD[w2 * 32 + row]);
      mnew[r] = fmaxf(m_run[r], mt);
      fct[r] = __expf(m_run[r] - mnew[r]);
      m_run[r] = mnew[r];
    }
    float psum[4] = {0.f, 0.f, 0.f, 0.f};
#pragma unroll
    for (int ct = 0; ct < 2; ++ct)
#pragma unroll
      for (int r = 0; r < 4; ++r) {
        float p = __expf(sacc[ct][r] - mnew[r]);
        psum[r] += p;
        float po = __shfl_xor(p, 1, 64);
        if (!(l & 1)) {
          const int row = wr * 16 + lg * 4 + r;
          *(uint*)(PB + row * 528 + (wc * 32 + ct * 16 + (li & 14)) * 2) = pack2(p, po);
        }
      }
#pragma unroll
    for (int off = 1; off <= 8; off <<= 1)
#pragma unroll
      for (int r = 0; r < 4; ++r) psum[r] += __shfl_xor(psum[r], off, 64);
    if (li == 0)
#pragma unroll
      for (int r = 0; r < 4; ++r) RD2[wc * 32 + wr * 16 + lg * 4 + r] = psum[r];
    __syncthreads();   // RD2 + PB now visible
#pragma unroll
    for (int r = 0; r < 4; ++r) {
      const int row = wr * 16 + lg * 4 + r;
      float ts = 0.f;
#pragma unroll
      for (int w2 = 0; w2 < 8; ++w2) ts += RD2[w2 * 32 + row];
      l_run[r] = l_run[r] * fct[r] + ts;
    }
#pragma unroll
    for (int ti = 0; ti < 8; ++ti)
#pragma unroll
      for (int r = 0; r < 4; ++r) Oacc[ti][r] *= fct[r];

    // ---- PV over j-chunks of 32 (V transposed into [h][j]) ----
    float4 v0[4], v1[4];
#pragma unroll
    for (int q = 0; q < 4; ++q) {
      v0[q] = ld4(xb + (size_t)(j0 + 2 * vjp) * HH + vhg * 16 + q * 4);
      v1[q] = ld4(xb + (size_t)(j0 + 2 * vjp + 1) * HH + vhg * 16 + q * 4);
    }
    for (int jc = 0; jc < 8; ++jc) {
      __syncthreads();
#pragma unroll
      for (int q = 0; q < 4; ++q) {
        float a0[4] = {v0[q].x, v0[q].y, v0[q].z, v0[q].w};
        float a1[4] = {v1[q].x, v1[q].y, v1[q].z, v1[q].w};
#pragma unroll
        for (int i = 0; i < 4; ++i) {
          const int h = vhg * 16 + q * 4 + i;
          *(uint*)(VB + h * 80 + vjp * 4) = pack2(a0[i], a1[i]);
        }
      }
      if (jc < 7) {
        const int jj = j0 + (jc + 1) * 32;
#pragma unroll
        for (int q = 0; q < 4; ++q) {
          v0[q] = ld4(xb + (size_t)(jj + 2 * vjp) * HH + vhg * 16 + q * 4);
          v1[q] = ld4(xb + (size_t)(jj + 2 * vjp + 1) * HH + vhg * 16 + q * 4);
        }
      }
      __syncthreads();
      f16x8 pa = *(const f16x8*)(PB + (wr * 16 + li) * 528 + jc * 64 + lg * 16);
#pragma unroll
      for (int ti = 0; ti < 8; ++ti) {
        const int h = wc * 128 + ti * 16 + li;
        f16x8 vb = *(const f16x8*)(VB + h * 80 + lg * 16);
        Oacc[ti] = MFMA(pa, vb, Oacc[ti]);
      }
    }
  }

  // ---- epilogue: normalize, residual, LN1, write h ----
  float musum[4] = {0.f, 0.f, 0.f, 0.f};
#pragma unroll
  for (int ti = 0; ti < 8; ++ti) {
    const int col = wc * 128 + ti * 16 + li;
#pragma unroll
    for (int r = 0; r < 4; ++r) {
      const int row = m0 + wr * 16 + lg * 4 + r;
      float v = xb[(size_t)row * HH + col] + Oacc[ti][r] / l_run[r];
      Oacc[ti][r] = v; musum[r] += v;
    }
  }
#pragma unroll
  for (int off = 1; off <= 8; off <<= 1)
#pragma unroll
    for (int r = 0; r < 4; ++r) musum[r] += __shfl_xor(musum[r], off, 64);
  if (li == 0)
#pragma unroll
    for (int r = 0; r < 4; ++r) RD[wc * 32 + wr * 16 + lg * 4 + r] = musum[r];
  __syncthreads();
  float mu[4];
#pragma unroll
  for (int r = 0; r < 4; ++r) {
    const int row = wr * 16 + lg * 4 + r;
    float s = 0.f;
#pragma unroll
    for (int w2 = 0; w2 < 8; ++w2) s += RD[w2 * 32 + row];
    mu[r] = s * (1.0f / HH);
  }
  float vsum[4] = {0.f, 0.f, 0.f, 0.f};
#pragma unroll
  for (int ti = 0; ti < 8; ++ti)
#pragma unroll
    for (int r = 0; r < 4; ++r) {
      float d = Oacc[ti][r] - mu[r]; vsum[r] += d * d;
    }
#pragma unroll
  for (int off = 1; off <= 8; off <<= 1)
#pragma unroll
    for (int r = 0; r < 4; ++r) vsum[r] += __shfl_xor(vsum[r], off, 64);
  if (li == 0)
#pragma unroll
    for (int r = 0; r < 4; ++r) RD2[wc * 32 + wr * 16 + lg * 4 + r] = vsum[r];
  __syncthreads();
  float rs[4];
#pragma unroll
  for (int r = 0; r < 4; ++r) {
    const int row = wr * 16 + lg * 4 + r;
    float s = 0.f;
#pragma unroll
    for (int w2 = 0; w2 < 8; ++w2) s += RD2[w2 * 32 + row];
    rs[r] = rsqrtf(s * (1.0f / HH) + EPS_);
  }
#pragma unroll
  for (int ti = 0; ti < 8; ++ti) {
    const int col = wc * 128 + ti * 16 + li;
    const float gv = g1[col], bv = lb1[col];
#pragma unroll
    for (int r = 0; r < 4; ++r) {
      const int row = m0 + wr * 16 + lg * 4 + r;
      hout[((size_t)b * NN + row) * HH + col] = (Oacc[ti][r] - mu[r]) * rs[r] * gv + bv;
    }
  }
}

// ---------------- ffn: out = LN2(h + GELU(h w1 + b1) w2 + b2) in place ----------------
// 1024 thr (16 waves), BM=64 rows/block, f-tiles of 256, f16 MFMA single precision.
// LDS: HB h[64][80] | W1B [256f][80] | GB g[64][528] | W2B [1024h][80] | RD/RD2
template<bool WS>
__global__ __launch_bounds__(1024)
void ffn_kernel(float* __restrict__ hio, const float* __restrict__ g2,
                const float* __restrict__ lb2,
                const float* __restrict__ w1, const float* __restrict__ b1f,
                const float* __restrict__ w2, const float* __restrict__ b2f,
                const f16* __restrict__ w1t, const f16* __restrict__ w2t) {
  extern __shared__ char smem[];
  char* HB  = smem;                // 5120
  char* W1B = smem + 5120;         // 20480
  char* GB  = smem + 25600;        // 33792
  char* W2B = smem + 59392;        // 81920
  float* RD  = (float*)(smem + 141312);
  float* RD2 = (float*)(smem + 142336);

  const int t = threadIdx.x, l = t & 63, w = t >> 6;
  const int lg = l >> 4, li = l & 15;
  const int rt = w >> 2, wc4 = w & 3;
  const int b = blockIdx.y, m0 = blockIdx.x * 64;
  float* __restrict__ hb = hio + ((size_t)b * NN + m0) * HH;

  f32x4 Oacc[16] = {};             // rows rt*16+lg*4+r, cols wc4*256+ti*16+li

  for (int ft = 0; ft < 16; ++ft) {
    const int f0 = ft * 256;
    f32x4 uacc[4] = {};
    // ---- mm1: u = h @ w1[:, f0:f0+256], k-chunks of 32 ----
    const int hr = t >> 4, hk2 = t & 15;           // hbuf: 64r x 16 float2
    float2 hv = *(const float2*)(hb + (size_t)hr * HH + hk2 * 2);
    f16x8 wv; float4 wf0, wf1;
    const int wfW = t >> 2, wkq = t & 3;           // WS: 256f x 4 x 8k
    const int ki = t & 31, fg = t >> 5;            // !WS: 32k x 32 x 8f
    if (WS) {
      wv = *(const f16x8*)(w1t + (size_t)(f0 + wfW) * HH + wkq * 8);
    } else {
      wf0 = ld4(w1 + (size_t)ki * FFD + f0 + fg * 8);
      wf1 = ld4(w1 + (size_t)ki * FFD + f0 + fg * 8 + 4);
    }
    for (int kc = 0; kc < 32; ++kc) {
      __syncthreads();
      *(uint*)(HB + hr * 80 + hk2 * 4) = pack2(hv.x, hv.y);
      if (WS) {
        *(f16x8*)(W1B + wfW * 80 + wkq * 16) = wv;
      } else {
        float vv[8] = {wf0.x, wf0.y, wf0.z, wf0.w, wf1.x, wf1.y, wf1.z, wf1.w};
#pragma unroll
        for (int i = 0; i < 8; ++i)
          *(ushort*)(W1B + (fg * 8 + i) * 80 + ki * 2) = h2u((f16)vv[i]);
      }
      if (kc < 31) {
        const int k0 = (kc + 1) * 32;
        hv = *(const float2*)(hb + (size_t)hr * HH + k0 + hk2 * 2);
        if (WS) wv = *(const f16x8*)(w1t + (size_t)(f0 + wfW) * HH + k0 + wkq * 8);
        else {
          wf0 = ld4(w1 + (size_t)(k0 + ki) * FFD + f0 + fg * 8);
          wf1 = ld4(w1 + (size_t)(k0 + ki) * FFD + f0 + fg * 8 + 4);
        }
      }
      __syncthreads();
      f16x8 af = *(const f16x8*)(HB + (rt * 16 + li) * 80 + lg * 16);
#pragma unroll
      for (int ct = 0; ct < 4; ++ct) {
        const int fc = wc4 * 64 + ct * 16 + li;
        f16x8 bf = *(const f16x8*)(W1B + fc * 80 + lg * 16);
        uacc[ct] = MFMA(af, bf, uacc[ct]);
      }
    }
    // ---- bias + GELU -> GB (f16, packed pairs) ----
    __syncthreads();
#pragma unroll
    for (int ct = 0; ct < 4; ++ct) {
      const int ucol = wc4 * 64 + ct * 16 + li;
      const float b1v = b1f[f0 + ucol];
#pragma unroll
      for (int r = 0; r < 4; ++r) {
        float g = gelu(uacc[ct][r] + b1v);
        float go = __shfl_xor(g, 1, 64);
        if (!(l & 1)) {
          const int row = rt * 16 + lg * 4 + r;
          *(uint*)(GB + row * 528 + (wc4 * 64 + ct * 16 + (li & 14)) * 2) = pack2(g, go);
        }
      }
    }
    __syncthreads();
    // ---- mm2: Oacc += g @ w2[f0:f0+256, :], f-chunks of 32 ----
    f16x8 wv2[4]; float4 fv[8];
    const int w2fi = t & 31, w2hg = t >> 5;        // !WS map
    if (WS) {
#pragma unroll
      for (int q = 0; q < 4; ++q)
        wv2[q] = *(const f16x8*)(w2t + (size_t)t * FFD + f0 + q * 8);
    } else {
#pragma unroll
      for (int q = 0; q < 8; ++q)
        fv[q] = ld4(w2 + (size_t)(f0 + w2fi) * HH + w2hg * 32 + q * 4);
    }
    for (int fc = 0; fc < 8; ++fc) {
      if (WS) {
#pragma unroll
        for (int q = 0; q < 4; ++q) *(f16x8*)(W2B + t * 80 + q * 16) = wv2[q];
      } else {
#pragma unroll
        for (int q = 0; q < 8; ++q) {
          float vv[4] = {fv[q].x, fv[q].y, fv[q].z, fv[q].w};
#pragma unroll
          for (int i = 0; i < 4; ++i)
            *(ushort*)(W2B + (w2hg * 32 + q * 4 + i) * 80 + w2fi * 2) = h2u((f16)vv[i]);
        }
      }
      if (fc < 7) {
        const int fk = f0 + (fc + 1) * 32;
        if (WS) {
#pragma unroll
          for (int q = 0; q < 4; ++q)
            wv2[q] = *(const f16x8*)(w2t + (size_t)t * FFD + fk + q * 8);
        } else {
#pragma unroll
          for (int q = 0; q < 8; ++q)
            fv[q] = ld4(w2 + (size_t)(fk + w2fi) * HH + w2hg * 32 + q * 4);
        }
      }
      __syncthreads();
      f16x8 ag = *(const f16x8*)(GB + (rt * 16 + li) * 528 + fc * 64 + lg * 16);
#pragma unroll
      for (int ti = 0; ti < 16; ++ti) {
        const int h = wc4 * 256 + ti * 16 + li;
        f16x8 bg = *(const f16x8*)(W2B + h * 80 + lg * 16);
        Oacc[ti] = MFMA(ag, bg, Oacc[ti]);
      }
      __syncthreads();
    }
  }

  // ---- epilogue: y = h + ffn + b2, LN2, write in place ----
  float musum[4] = {0.f, 0.f, 0.f, 0.f};
#pragma unroll
  for (int ti = 0; ti < 16; ++ti) {
    const int col = wc4 * 256 + ti * 16 + li;
    const float b2v = b2f[col];
#pragma unroll
    for (int r = 0; r < 4; ++r) {
      const int row = rt * 16 + lg * 4 + r;
      float v = hb[(size_t)row * HH + col] + Oacc[ti][r] + b2v;
      Oacc[ti][r] = v; musum[r] += v;
    }
  }
#pragma unroll
  for (int off = 1; off <= 8; off <<= 1)
#pragma unroll
    for (int r = 0; r < 4; ++r) musum[r] += __shfl_xor(musum[r], off, 64);
  if (li == 0)
#pragma unroll
    for (int r = 0; r < 4; ++r) RD[wc4 * 64 + rt * 16 + lg * 4 + r] = musum[r];
  __syncthreads();
  float mu[4];
#pragma unroll
  for (int r = 0; r < 4; ++r) {
    const int row = rt * 16 + lg * 4 + r;
    float s = 0.f;
#pragma unroll
    for (int w2i = 0; w2i < 4; ++w2i) s += RD[w2i * 64 + row];
    mu[r] = s * (1.0f / HH);
  }
  float vsum[4] = {0.f, 0.f, 0.f, 0.f};
#pragma unroll
  for (int ti = 0; ti < 16; ++ti)
#pragma unroll
    for (int r = 0; r < 4; ++r) { float d = Oacc[ti][r] - mu[r]; vsum[r] += d * d; }
#pragma unroll
  for (int off = 1; off <= 8; off <<= 1)
#pragma unroll
    for (int r = 0; r < 4; ++r) vsum[r] += __shfl_xor(vsum[r], off, 64);
  if (li == 0)
#pragma unroll
    for (int r = 0; r < 4; ++r) RD2[wc4 * 64 + rt * 16 + lg * 4 + r] = vsum[r];
  __syncthreads();
  float rs[4];
#pragma unroll
  for (int r = 0; r < 4; ++r) {
    const int row = rt * 16 + lg * 4 + r;
    float s = 0.f;
#pragma unroll
    for (int w2i = 0; w2i < 4; ++w2i) s += RD2[w2i * 64 + row];
    rs[r] = rsqrtf(s * (1.0f / HH) + EPS_);
  }
#pragma unroll
  for (int ti = 0; ti < 16; ++ti) {
    const int col = wc4 * 256 + ti * 16 + li;
    const float gv = g2[col], bv = lb2[col];
#pragma unroll
    for (int r = 0; r < 4; ++r) {
      const int row = rt * 16 + lg * 4 + r;
      hb[(size_t)row * HH + col] = (Oacc[ti][r] - mu[r]) * rs[r] * gv + bv;
    }
  }
}

extern "C" void kernel_launch(void* const* d_in, const int* in_sizes, int n_in,
                              void* d_out, int out_size, void* d_ws, size_t ws_size,
                              hipStream_t stream) {
  (void)in_sizes; (void)n_in; (void)out_size;
  const float* x    = (const float*)d_in[0];
  const float* ln1g = (const float*)d_in[1];
  const float* ln1b = (const float*)d_in[2];
  const float* ln2g = (const float*)d_in[3];
  const float* ln2b = (const float*)d_in[4];
  const float* w1   = (const float*)d_in[5];
  const float* bb1  = (const float*)d_in[6];
  const float* w2   = (const float*)d_in[7];
  const float* bb2  = (const float*)d_in[8];
  float* out = (float*)d_out;

  const size_t wbytes = (size_t)2 * FFD * HH * sizeof(f16);  // 16 MiB
  const bool ws_ok = (ws_size >= wbytes) && (d_ws != nullptr);
  f16* w1t = (f16*)d_ws;
  f16* w2t = w1t + (size_t)FFD * HH;

  (void)hipFuncSetAttribute((const void*)attn_kernel,
                            hipFuncAttributeMaxDynamicSharedMemorySize, 146944);
  (void)hipFuncSetAttribute((const void*)ffn_kernel<true>,
                            hipFuncAttributeMaxDynamicSharedMemorySize, 143360);
  (void)hipFuncSetAttribute((const void*)ffn_kernel<false>,
                            hipFuncAttributeMaxDynamicSharedMemorySize, 143360);

  if (ws_ok) {
    transpose_f16<<<dim3(FFD / 32, HH / 32), 256, 0, stream>>>(w1, w1t, HH, FFD);
    transpose_f16<<<dim3(HH / 32, FFD / 32), 256, 0, stream>>>(w2, w2t, FFD, HH);
  }
  attn_kernel<<<dim3(NN / 32, NB), 1024, 146944, stream>>>(x, ln1g, ln1b, out);
  if (ws_ok)
    ffn_kernel<true><<<dim3(NN / 64, NB), 1024, 143360, stream>>>(
        out, ln2g, ln2b, w1, bb1, w2, bb2, w1t, w2t);
  else
    ffn_kernel<false><<<dim3(NN / 64, NB), 1024, 143360, stream>>>(
        out, ln2g, ln2b, w1, bb1, w2, bb2, nullptr, nullptr);
}

// Round 4
// 1666.209 us; speedup vs baseline: 4.9666x; 1.2246x over previous
//
#include <hip/hip_runtime.h>
#include <stdint.h>

#define NB 8
#define NN 2048
#define HH 1024
#define FFD 4096
#define M2 8
constexpr float EPS_ = 1e-5f;

typedef _Float16 f16;
typedef _Float16 f16x8 __attribute__((ext_vector_type(8)));
typedef float f32x4 __attribute__((ext_vector_type(4)));
typedef float f32x16 __attribute__((ext_vector_type(16)));

__device__ __forceinline__ f32x4 MFMA16(f16x8 a, f16x8 b, f32x4 c) {
  return __builtin_amdgcn_mfma_f32_16x16x32_f16(a, b, c, 0, 0, 0);
}
__device__ __forceinline__ f32x16 MFMA32(f16x8 a, f16x8 b, f32x16 c) {
  return __builtin_amdgcn_mfma_f32_32x32x16_f16(a, b, c, 0, 0, 0);
}
__device__ __forceinline__ ushort h2u(f16 h) { union { f16 h; ushort u; } v; v.h = h; return v.u; }
__device__ __forceinline__ unsigned pack2(float a, float b) {
  return (unsigned)h2u((f16)a) | ((unsigned)h2u((f16)b) << 16);
}
__device__ __forceinline__ float4 ld4(const float* p) { return *(const float4*)p; }
__device__ __forceinline__ float gelu(float u) {
  return 0.5f * u * (1.0f + erff(u * 0.70710678118654752f));
}
// async global->LDS, 16B per lane; LDS dest = uniform base + lane*16
__device__ __forceinline__ void gload16(const void* g, void* l) {
  __builtin_amdgcn_global_load_lds(
      (const __attribute__((address_space(1))) unsigned int*)g,
      (__attribute__((address_space(3))) unsigned int*)l, 16, 0, 0);
}

// ---------------- prep: x -> f16 hi/lo split ----------------
__global__ void convert_hl(const float* __restrict__ x, f16* __restrict__ xh,
                           f16* __restrict__ xl) {
  const size_t i = ((size_t)blockIdx.x * blockDim.x + threadIdx.x) * 4;
  float4 v = ld4(x + i);
  f16 h0 = (f16)v.x, h1 = (f16)v.y, h2 = (f16)v.z, h3 = (f16)v.w;
  ushort4 ho = {h2u(h0), h2u(h1), h2u(h2), h2u(h3)};
  ushort4 lo = {h2u((f16)(v.x - (float)h0)), h2u((f16)(v.y - (float)h1)),
                h2u((f16)(v.z - (float)h2)), h2u((f16)(v.w - (float)h3))};
  *(ushort4*)(xh + i) = ho;
  *(ushort4*)(xl + i) = lo;
}

// ---------------- prep: transpose fp32 -> f16, dst[C][R] = (f16)src[R][C] ----------------
__global__ void transpose_f16k(const float* __restrict__ src, f16* __restrict__ dst,
                               int R, int C, long sbs, long dbs) {
  __shared__ float tl[32][33];
  src += (size_t)blockIdx.z * sbs;
  dst += (size_t)blockIdx.z * dbs;
  const int t = threadIdx.x;
  const int c0 = blockIdx.x * 32, r0 = blockIdx.y * 32;
  {
    const int r = t >> 3, c4 = t & 7;
    float4 v = ld4(src + (size_t)(r0 + r) * C + c0 + c4 * 4);
    tl[r][c4 * 4 + 0] = v.x; tl[r][c4 * 4 + 1] = v.y;
    tl[r][c4 * 4 + 2] = v.z; tl[r][c4 * 4 + 3] = v.w;
  }
  __syncthreads();
  {
    const int c = t >> 3, r4 = t & 7;
    ushort4 o;
    o.x = h2u((f16)tl[r4 * 4 + 0][c]);
    o.y = h2u((f16)tl[r4 * 4 + 1][c]);
    o.z = h2u((f16)tl[r4 * 4 + 2][c]);
    o.w = h2u((f16)tl[r4 * 4 + 3][c]);
    *(ushort4*)(dst + (size_t)(c0 + c) * R + r0 + r4 * 4) = o;
  }
}

// ---------------- attn v2: flash, 512 thr / 8 waves, BM=64, 32x32x16 MFMA ----------------
// LDS: REG 64KB (QK: KB[2][hi16K|lo16K] / PV: VB[2][32K]) | PB 64x528B | reduce bufs
#define RSTR 528
// stage K hi/lo chunk [256 keys][32 k] f16 via global_load_lds, src-swizzled
__device__ __forceinline__ void stageKB(char* REGb, const f16* xhb, const f16* xlb,
                                        int j0, int k0, int w, int l) {
#pragma unroll
  for (int r = 0; r < 2; ++r) {
    const int grp = r * 8 + w;                 // 16 rows per instr
    const int j = grp * 16 + (l >> 2);
    const int clog = (l & 3) ^ ((j >> 1) & 3);
    const size_t src = (size_t)(j0 + j) * HH + k0 + clog * 8;
    gload16(xhb + src, REGb + grp * 1024);
    gload16(xlb + src, REGb + 16384 + grp * 1024);
  }
}
// stage V^T chunk [1024 h][16 j] f16
__device__ __forceinline__ void stageVB(char* VBb, const f16* xtb, int jabs, int w, int l) {
#pragma unroll
  for (int r = 0; r < 4; ++r) {
    const int grp = r * 8 + w;                 // 32 rows per instr
    const int h = grp * 32 + (l >> 1);
    const int clog = (l & 1) ^ ((h >> 2) & 1);
    gload16(xtb + (size_t)h * NN + jabs + clog * 8, VBb + grp * 1024);
  }
}

__global__ __launch_bounds__(512, 2)
void attn_v2(const float* __restrict__ x, const f16* __restrict__ xh,
             const f16* __restrict__ xl, const f16* __restrict__ xt,
             const float* __restrict__ g1, const float* __restrict__ lb1,
             float* __restrict__ hout) {
  extern __shared__ char smem[];
  char* REG = smem;                         // 65536
  char* PB  = smem + 65536;                 // 33792
  float* RD   = (float*)(smem + 99328);     // [4][64]
  float* mrow = (float*)(smem + 100352);    // [64]
  float* lrow = (float*)(smem + 100608);    // [64]
  float* fctb = (float*)(smem + 100864);    // [64]

  const int t = threadIdx.x, l = t & 63, w = t >> 6;
  const int l31 = l & 31, lh = l >> 5;
  const int wr = w >> 2, wc = w & 3;
  const int b = blockIdx.y, m0 = blockIdx.x * 64;
  const f16* __restrict__ xhb = xh + (size_t)b * NN * HH;
  const f16* __restrict__ xlb = xl + (size_t)b * NN * HH;
  const f16* __restrict__ xtb = xt + (size_t)b * HH * NN;
  const float* __restrict__ xb = x + (size_t)b * NN * HH;

  if (t < 64) { mrow[t] = -INFINITY; lrow[t] = 0.f; }

  f32x16 Oacc[8] = {};                      // rows wr*32+pat, cols wc*256+ht*32+l31
  const int arow = m0 + wr * 32 + l31;      // this lane's Q row (A-frag)

  for (int jt = 0; jt < 8; ++jt) {
    const int j0 = jt * 256;
    f32x16 sacc[2] = {};

    // ---------- QK: K in chunks of 32, KB double-buffered, Q prefetched to regs ----------
    f16x8 ah[2], al[2];
#pragma unroll
    for (int s = 0; s < 2; ++s) {
      ah[s] = *(const f16x8*)(xhb + (size_t)arow * HH + s * 16 + lh * 8);
      al[s] = *(const f16x8*)(xlb + (size_t)arow * HH + s * 16 + lh * 8);
    }
    stageKB(REG, xhb, xlb, j0, 0, w, l);
    __syncthreads();
    int buf = 0;
    for (int kc = 0; kc < 32; ++kc) {
      f16x8 nh[2], nl[2];
      if (kc < 31) {
        stageKB(REG + (buf ^ 1) * 32768, xhb, xlb, j0, (kc + 1) * 32, w, l);
        const int kn = (kc + 1) * 32;
#pragma unroll
        for (int s = 0; s < 2; ++s) {
          nh[s] = *(const f16x8*)(xhb + (size_t)arow * HH + kn + s * 16 + lh * 8);
          nl[s] = *(const f16x8*)(xlb + (size_t)arow * HH + kn + s * 16 + lh * 8);
        }
      }
      const char* KH = REG + buf * 32768;
      const char* KL = KH + 16384;
#pragma unroll
      for (int ct = 0; ct < 2; ++ct) {
        const int j = wc * 64 + ct * 32 + l31;
        const int swz = (j >> 1) & 3;
        const char* rowH = KH + j * 64;
        const char* rowL = KL + j * 64;
#pragma unroll
        for (int s = 0; s < 2; ++s) {
          const int cp = (s * 2 + lh) ^ swz;
          f16x8 bh = *(const f16x8*)(rowH + cp * 16);
          f16x8 bl = *(const f16x8*)(rowL + cp * 16);
          sacc[ct] = MFMA32(ah[s], bh, sacc[ct]);   // hi*hi
          sacc[ct] = MFMA32(al[s], bh, sacc[ct]);   // lo(Q)*hi(K)
          sacc[ct] = MFMA32(ah[s], bl, sacc[ct]);   // hi*lo(K)
        }
      }
      __syncthreads();
      if (kc < 31) {
#pragma unroll
        for (int s = 0; s < 2; ++s) { ah[s] = nh[s]; al[s] = nl[s]; }
      }
      buf ^= 1;
    }

    // ---------- online softmax ----------
    float tmax[16];
#pragma unroll
    for (int rg = 0; rg < 16; ++rg) tmax[rg] = fmaxf(sacc[0][rg], sacc[1][rg]);
#pragma unroll
    for (int off = 1; off <= 16; off <<= 1)
#pragma unroll
      for (int rg = 0; rg < 16; ++rg) tmax[rg] = fmaxf(tmax[rg], __shfl_xor(tmax[rg], off, 64));
    if (l31 == 0) {
#pragma unroll
      for (int rg = 0; rg < 16; ++rg) {
        const int rl = (rg & 3) + 8 * (rg >> 2) + 4 * lh;
        RD[wc * 64 + wr * 32 + rl] = tmax[rg];
      }
    }
    __syncthreads();
    if (t < 64) {
      float mt = fmaxf(fmaxf(RD[t], RD[64 + t]), fmaxf(RD[128 + t], RD[192 + t]));
      float mo = mrow[t];
      float mn = fmaxf(mo, mt);
      mrow[t] = mn;
      fctb[t] = __expf(mo - mn);
    }
    __syncthreads();
    float mv[16], psum[16];
#pragma unroll
    for (int rg = 0; rg < 16; ++rg)
      mv[rg] = mrow[wr * 32 + (rg & 3) + 8 * (rg >> 2) + 4 * lh];
#pragma unroll
    for (int ct = 0; ct < 2; ++ct) {
#pragma unroll
      for (int rg = 0; rg < 16; ++rg) {
        float p = __expf(sacc[ct][rg] - mv[rg]);
        if (ct == 0) psum[rg] = p; else psum[rg] += p;
        float po = __shfl_xor(p, 1, 64);
        if (!(l & 1)) {
          const int R = wr * 32 + (rg & 3) + 8 * (rg >> 2) + 4 * lh;
          const int col = wc * 64 + ct * 32 + l31;
          *(unsigned*)(PB + R * RSTR + col * 2) = pack2(p, po);
        }
      }
    }
#pragma unroll
    for (int off = 1; off <= 16; off <<= 1)
#pragma unroll
      for (int rg = 0; rg < 16; ++rg) psum[rg] += __shfl_xor(psum[rg], off, 64);
    if (l31 == 0) {
#pragma unroll
      for (int rg = 0; rg < 16; ++rg) {
        const int rl = (rg & 3) + 8 * (rg >> 2) + 4 * lh;
        RD[wc * 64 + wr * 32 + rl] = psum[rg];
      }
    }
    __syncthreads();
    if (t < 64) lrow[t] = lrow[t] * fctb[t] + (RD[t] + RD[64 + t] + RD[128 + t] + RD[192 + t]);
    float fv[16];
#pragma unroll
    for (int rg = 0; rg < 16; ++rg)
      fv[rg] = fctb[wr * 32 + (rg & 3) + 8 * (rg >> 2) + 4 * lh];
#pragma unroll
    for (int ht = 0; ht < 8; ++ht)
#pragma unroll
      for (int rg = 0; rg < 16; ++rg) Oacc[ht][rg] *= fv[rg];

    // ---------- PV: 16-key chunks, VB double-buffered ----------
    stageVB(REG, xtb, j0, w, l);
    __syncthreads();
    int vbuf = 0;
    for (int jc = 0; jc < 16; ++jc) {
      if (jc < 15) stageVB(REG + (vbuf ^ 1) * 32768, xtb, j0 + (jc + 1) * 16, w, l);
      const char* VBc = REG + vbuf * 32768;
      f16x8 pa = *(const f16x8*)(PB + (wr * 32 + l31) * RSTR + (jc * 2 + lh) * 16);
#pragma unroll
      for (int ht = 0; ht < 8; ++ht) {
        const int h = wc * 256 + ht * 32 + l31;
        f16x8 vb = *(const f16x8*)(VBc + h * 32 + ((lh ^ ((h >> 2) & 1)) * 16));
        Oacc[ht] = MFMA32(pa, vb, Oacc[ht]);
      }
      __syncthreads();
      vbuf ^= 1;
    }
  }

  // ---------- epilogue: normalize, residual, LN1 ----------
  float lv[16];
#pragma unroll
  for (int rg = 0; rg < 16; ++rg)
    lv[rg] = 1.0f / lrow[wr * 32 + (rg & 3) + 8 * (rg >> 2) + 4 * lh];
  float musum[16];
#pragma unroll
  for (int rg = 0; rg < 16; ++rg) musum[rg] = 0.f;
#pragma unroll
  for (int ht = 0; ht < 8; ++ht) {
    const int col = wc * 256 + ht * 32 + l31;
#pragma unroll
    for (int rg = 0; rg < 16; ++rg) {
      const int R = wr * 32 + (rg & 3) + 8 * (rg >> 2) + 4 * lh;
      float v = fmaf(Oacc[ht][rg], lv[rg], xb[(size_t)(m0 + R) * HH + col]);
      Oacc[ht][rg] = v; musum[rg] += v;
    }
  }
#pragma unroll
  for (int off = 1; off <= 16; off <<= 1)
#pragma unroll
    for (int rg = 0; rg < 16; ++rg) musum[rg] += __shfl_xor(musum[rg], off, 64);
  if (l31 == 0) {
#pragma unroll
    for (int rg = 0; rg < 16; ++rg) {
      const int rl = (rg & 3) + 8 * (rg >> 2) + 4 * lh;
      RD[wc * 64 + wr * 32 + rl] = musum[rg];
    }
  }
  __syncthreads();
  if (t < 64) mrow[t] = (RD[t] + RD[64 + t] + RD[128 + t] + RD[192 + t]) * (1.0f / HH);
  __syncthreads();
  float mu[16], vsum[16];
#pragma unroll
  for (int rg = 0; rg < 16; ++rg) {
    mu[rg] = mrow[wr * 32 + (rg & 3) + 8 * (rg >> 2) + 4 * lh];
    vsum[rg] = 0.f;
  }
#pragma unroll
  for (int ht = 0; ht < 8; ++ht)
#pragma unroll
    for (int rg = 0; rg < 16; ++rg) {
      float d = Oacc[ht][rg] - mu[rg];
      vsum[rg] += d * d;
    }
#pragma unroll
  for (int off = 1; off <= 16; off <<= 1)
#pragma unroll
    for (int rg = 0; rg < 16; ++rg) vsum[rg] += __shfl_xor(vsum[rg], off, 64);
  if (l31 == 0) {
#pragma unroll
    for (int rg = 0; rg < 16; ++rg) {
      const int rl = (rg & 3) + 8 * (rg >> 2) + 4 * lh;
      RD[wc * 64 + wr * 32 + rl] = vsum[rg];
    }
  }
  __syncthreads();
  if (t < 64) fctb[t] = rsqrtf((RD[t] + RD[64 + t] + RD[128 + t] + RD[192 + t]) * (1.0f / HH) + EPS_);
  __syncthreads();
  float rs[16];
#pragma unroll
  for (int rg = 0; rg < 16; ++rg)
    rs[rg] = fctb[wr * 32 + (rg & 3) + 8 * (rg >> 2) + 4 * lh];
#pragma unroll
  for (int ht = 0; ht < 8; ++ht) {
    const int col = wc * 256 + ht * 32 + l31;
    const float gv = g1[col], bv = lb1[col];
#pragma unroll
    for (int rg = 0; rg < 16; ++rg) {
      const int R = wr * 32 + (rg & 3) + 8 * (rg >> 2) + 4 * lh;
      hout[((size_t)b * NN + m0 + R) * HH + col] = (Oacc[ht][rg] - mu[rg]) * rs[rg] * gv + bv;
    }
  }
}

// ---------------- legacy attn (r3, fallback when ws too small) ----------------
__global__ __launch_bounds__(1024)
void attn_legacy(const float* __restrict__ x, const float* __restrict__ g1,
                 const float* __restrict__ lb1, float* __restrict__ hout) {
  extern __shared__ char smem[];
  char* AB = smem;
  char* BB = smem + 5120;
  char* PB2 = smem + 46080;
  char* VB = smem + 62976;
  float* RD  = (float*)(smem + 144896);
  float* RD2 = (float*)(smem + 145920);

  const int t = threadIdx.x, l = t & 63, w = t >> 6;
  const int lg = l >> 4, li = l & 15;
  const int wr = w >> 3, wc = w & 7;
  const int b = blockIdx.y, m0 = blockIdx.x * 32;
  const float* __restrict__ xb = x + (size_t)b * NN * HH;

  const int ar = t >> 5, ak = t & 31;
  const int bj = t >> 2, bq = t & 3;
  const int vjp = t & 15, vhg = t >> 4;

  f32x4 Oacc[8] = {};
  float m_run[4] = {-INFINITY, -INFINITY, -INFINITY, -INFINITY};
  float l_run[4] = {0.f, 0.f, 0.f, 0.f};

  for (int jt = 0; jt < 8; ++jt) {
    const int j0 = jt * 256;
    f32x4 sacc[2] = {};
    float qv = xb[(size_t)(m0 + ar) * HH + ak];
    float4 ca = ld4(xb + (size_t)(j0 + bj) * HH + bq * 8);
    float4 cb = ld4(xb + (size_t)(j0 + bj) * HH + bq * 8 + 4);
    for (int kc = 0; kc < 32; ++kc) {
      __syncthreads();
      {
        f16 qh = (f16)qv; f16 ql = (f16)(qv - (float)qh);
        *(ushort*)(AB + ar * 80 + ak * 2) = h2u(qh);
        *(ushort*)(AB + 2560 + ar * 80 + ak * 2) = h2u(ql);
        float vv[8] = {ca.x, ca.y, ca.z, ca.w, cb.x, cb.y, cb.z, cb.w};
        f16x8 hi8, lo8;
#pragma unroll
        for (int i = 0; i < 8; ++i) {
          f16 h = (f16)vv[i]; hi8[i] = h; lo8[i] = (f16)(vv[i] - (float)h);
        }
        *(f16x8*)(BB + bj * 80 + bq * 16) = hi8;
        *(f16x8*)(BB + 20480 + bj * 80 + bq * 16) = lo8;
      }
      if (kc < 31) {
        const int k0 = (kc + 1) * 32;
        qv = xb[(size_t)(m0 + ar) * HH + k0 + ak];
        ca = ld4(xb + (size_t)(j0 + bj) * HH + k0 + bq * 8);
        cb = ld4(xb + (size_t)(j0 + bj) * HH + k0 + bq * 8 + 4);
      }
      __syncthreads();
      const int arow = wr * 16 + li;
      f16x8 ahi = *(const f16x8*)(AB + arow * 80 + lg * 16);
      f16x8 alo = *(const f16x8*)(AB + 2560 + arow * 80 + lg * 16);
#pragma unroll
      for (int ct = 0; ct < 2; ++ct) {
        const int j = wc * 32 + ct * 16 + li;
        f16x8 bhi = *(const f16x8*)(BB + j * 80 + lg * 16);
        f16x8 blo = *(const f16x8*)(BB + 20480 + j * 80 + lg * 16);
        sacc[ct] = MFMA16(ahi, bhi, sacc[ct]);
        sacc[ct] = MFMA16(ahi, blo, sacc[ct]);
        sacc[ct] = MFMA16(alo, bhi, sacc[ct]);
      }
    }
    float m[4];
#pragma unroll
    for (int r = 0; r < 4; ++r) m[r] = fmaxf(sacc[0][r], sacc[1][r]);
#pragma unroll
    for (int off = 1; off <= 8; off <<= 1)
#pragma unroll
      for (int r = 0; r < 4; ++r) m[r] = fmaxf(m[r], __shfl_xor(m[r], off, 64));
    if (li == 0)
#pragma unroll
      for (int r = 0; r < 4; ++r) RD[wc * 32 + wr * 16 + lg * 4 + r] = m[r];
    __syncthreads();
    float mnew[4], fct[4];
#pragma unroll
    for (int r = 0; r < 4; ++r) {
      const int row = wr * 16 + lg * 4 + r;
      float mt = RD[row];
#pragma unroll
      for (int w2 = 1; w2 < 8; ++w2) mt = fmaxf(mt, RD[w2 * 32 + row]);
      mnew[r] = fmaxf(m_run[r], mt);
      fct[r] = __expf(m_run[r] - mnew[r]);
      m_run[r] = mnew[r];
    }
    float psum[4] = {0.f, 0.f, 0.f, 0.f};
#pragma unroll
    for (int ct = 0; ct < 2; ++ct)
#pragma unroll
      for (int r = 0; r < 4; ++r) {
        float p = __expf(sacc[ct][r] - mnew[r]);
        psum[r] += p;
        float po = __shfl_xor(p, 1, 64);
        if (!(l & 1)) {
          const int row = wr * 16 + lg * 4 + r;
          *(unsigned*)(PB2 + row * 528 + (wc * 32 + ct * 16 + (li & 14)) * 2) = pack2(p, po);
        }
      }
#pragma unroll
    for (int off = 1; off <= 8; off <<= 1)
#pragma unroll
      for (int r = 0; r < 4; ++r) psum[r] += __shfl_xor(psum[r], off, 64);
    if (li == 0)
#pragma unroll
      for (int r = 0; r < 4; ++r) RD2[wc * 32 + wr * 16 + lg * 4 + r] = psum[r];
    __syncthreads();
#pragma unroll
    for (int r = 0; r < 4; ++r) {
      const int row = wr * 16 + lg * 4 + r;
      float ts = 0.f;
#pragma unroll
      for (int w2 = 0; w2 < 8; ++w2) ts += RD2[w2 * 32 + row];
      l_run[r] = l_run[r] * fct[r] + ts;
    }
#pragma unroll
    for (int ti = 0; ti < 8; ++ti)
#pragma unroll
      for (int r = 0; r < 4; ++r) Oacc[ti][r] *= fct[r];

    float4 v0[4], v1[4];
#pragma unroll
    for (int q = 0; q < 4; ++q) {
      v0[q] = ld4(xb + (size_t)(j0 + 2 * vjp) * HH + vhg * 16 + q * 4);
      v1[q] = ld4(xb + (size_t)(j0 + 2 * vjp + 1) * HH + vhg * 16 + q * 4);
    }
    for (int jc = 0; jc < 8; ++jc) {
      __syncthreads();
#pragma unroll
      for (int q = 0; q < 4; ++q) {
        float a0[4] = {v0[q].x, v0[q].y, v0[q].z, v0[q].w};
        float a1[4] = {v1[q].x, v1[q].y, v1[q].z, v1[q].w};
#pragma unroll
        for (int i = 0; i < 4; ++i) {
          const int h = vhg * 16 + q * 4 + i;
          *(unsigned*)(VB + h * 80 + vjp * 4) = pack2(a0[i], a1[i]);
        }
      }
      if (jc < 7) {
        const int jj = j0 + (jc + 1) * 32;
#pragma unroll
        for (int q = 0; q < 4; ++q) {
          v0[q] = ld4(xb + (size_t)(jj + 2 * vjp) * HH + vhg * 16 + q * 4);
          v1[q] = ld4(xb + (size_t)(jj + 2 * vjp + 1) * HH + vhg * 16 + q * 4);
        }
      }
      __syncthreads();
      f16x8 pa = *(const f16x8*)(PB2 + (wr * 16 + li) * 528 + jc * 64 + lg * 16);
#pragma unroll
      for (int ti = 0; ti < 8; ++ti) {
        const int h = wc * 128 + ti * 16 + li;
        f16x8 vb = *(const f16x8*)(VB + h * 80 + lg * 16);
        Oacc[ti] = MFMA16(pa, vb, Oacc[ti]);
      }
    }
  }

  float musum[4] = {0.f, 0.f, 0.f, 0.f};
#pragma unroll
  for (int ti = 0; ti < 8; ++ti) {
    const int col = wc * 128 + ti * 16 + li;
#pragma unroll
    for (int r = 0; r < 4; ++r) {
      const int row = m0 + wr * 16 + lg * 4 + r;
      float v = xb[(size_t)row * HH + col] + Oacc[ti][r] / l_run[r];
      Oacc[ti][r] = v; musum[r] += v;
    }
  }
#pragma unroll
  for (int off = 1; off <= 8; off <<= 1)
#pragma unroll
    for (int r = 0; r < 4; ++r) musum[r] += __shfl_xor(musum[r], off, 64);
  if (li == 0)
#pragma unroll
    for (int r = 0; r < 4; ++r) RD[wc * 32 + wr * 16 + lg * 4 + r] = musum[r];
  __syncthreads();
  float mu[4];
#pragma unroll
  for (int r = 0; r < 4; ++r) {
    const int row = wr * 16 + lg * 4 + r;
    float s = 0.f;
#pragma unroll
    for (int w2 = 0; w2 < 8; ++w2) s += RD[w2 * 32 + row];
    mu[r] = s * (1.0f / HH);
  }
  float vsum[4] = {0.f, 0.f, 0.f, 0.f};
#pragma unroll
  for (int ti = 0; ti < 8; ++ti)
#pragma unroll
    for (int r = 0; r < 4; ++r) {
      float d = Oacc[ti][r] - mu[r]; vsum[r] += d * d;
    }
#pragma unroll
  for (int off = 1; off <= 8; off <<= 1)
#pragma unroll
    for (int r = 0; r < 4; ++r) vsum[r] += __shfl_xor(vsum[r], off, 64);
  if (li == 0)
#pragma unroll
    for (int r = 0; r < 4; ++r) RD2[wc * 32 + wr * 16 + lg * 4 + r] = vsum[r];
  __syncthreads();
  float rs[4];
#pragma unroll
  for (int r = 0; r < 4; ++r) {
    const int row = wr * 16 + lg * 4 + r;
    float s = 0.f;
#pragma unroll
    for (int w2 = 0; w2 < 8; ++w2) s += RD2[w2 * 32 + row];
    rs[r] = rsqrtf(s * (1.0f / HH) + EPS_);
  }
#pragma unroll
  for (int ti = 0; ti < 8; ++ti) {
    const int col = wc * 128 + ti * 16 + li;
    const float gv = g1[col], bv = lb1[col];
#pragma unroll
    for (int r = 0; r < 4; ++r) {
      const int row = m0 + wr * 16 + lg * 4 + r;
      hout[((size_t)b * NN + row) * HH + col] = (Oacc[ti][r] - mu[r]) * rs[r] * gv + bv;
    }
  }
}

// ---------------- ffn: unchanged from r3 ----------------
template<bool WS>
__global__ __launch_bounds__(1024)
void ffn_kernel(float* __restrict__ hio, const float* __restrict__ g2,
                const float* __restrict__ lb2,
                const float* __restrict__ w1, const float* __restrict__ b1f,
                const float* __restrict__ w2, const float* __restrict__ b2f,
                const f16* __restrict__ w1t, const f16* __restrict__ w2t) {
  extern __shared__ char smem[];
  char* HB  = smem;
  char* W1B = smem + 5120;
  char* GB  = smem + 25600;
  char* W2B = smem + 59392;
  float* RD  = (float*)(smem + 141312);
  float* RD2 = (float*)(smem + 142336);

  const int t = threadIdx.x, l = t & 63;
  const int w = t >> 6;
  const int lg = l >> 4, li = l & 15;
  const int rt = w >> 2, wc4 = w & 3;
  const int b = blockIdx.y, m0 = blockIdx.x * 64;
  float* __restrict__ hb = hio + ((size_t)b * NN + m0) * HH;

  f32x4 Oacc[16] = {};

  for (int ft = 0; ft < 16; ++ft) {
    const int f0 = ft * 256;
    f32x4 uacc[4] = {};
    const int hr = t >> 4, hk2 = t & 15;
    float2 hv = *(const float2*)(hb + (size_t)hr * HH + hk2 * 2);
    f16x8 wv; float4 wf0, wf1;
    const int wfW = t >> 2, wkq = t & 3;
    const int ki = t & 31, fg = t >> 5;
    if (WS) {
      wv = *(const f16x8*)(w1t + (size_t)(f0 + wfW) * HH + wkq * 8);
    } else {
      wf0 = ld4(w1 + (size_t)ki * FFD + f0 + fg * 8);
      wf1 = ld4(w1 + (size_t)ki * FFD + f0 + fg * 8 + 4);
    }
    for (int kc = 0; kc < 32; ++kc) {
      __syncthreads();
      *(unsigned*)(HB + hr * 80 + hk2 * 4) = pack2(hv.x, hv.y);
      if (WS) {
        *(f16x8*)(W1B + wfW * 80 + wkq * 16) = wv;
      } else {
        float vv[8] = {wf0.x, wf0.y, wf0.z, wf0.w, wf1.x, wf1.y, wf1.z, wf1.w};
#pragma unroll
        for (int i = 0; i < 8; ++i)
          *(ushort*)(W1B + (fg * 8 + i) * 80 + ki * 2) = h2u((f16)vv[i]);
      }
      if (kc < 31) {
        const int k0 = (kc + 1) * 32;
        hv = *(const float2*)(hb + (size_t)hr * HH + k0 + hk2 * 2);
        if (WS) wv = *(const f16x8*)(w1t + (size_t)(f0 + wfW) * HH + k0 + wkq * 8);
        else {
          wf0 = ld4(w1 + (size_t)(k0 + ki) * FFD + f0 + fg * 8);
          wf1 = ld4(w1 + (size_t)(k0 + ki) * FFD + f0 + fg * 8 + 4);
        }
      }
      __syncthreads();
      f16x8 af = *(const f16x8*)(HB + (rt * 16 + li) * 80 + lg * 16);
#pragma unroll
      for (int ct = 0; ct < 4; ++ct) {
        const int fc = wc4 * 64 + ct * 16 + li;
        f16x8 bf = *(const f16x8*)(W1B + fc * 80 + lg * 16);
        uacc[ct] = MFMA16(af, bf, uacc[ct]);
      }
    }
    __syncthreads();
    {
      const float4 b1v = *(const float4*)(b1f + f0 + 4 * t);
      (void)b1v;
    }
#pragma unroll
    for (int ct = 0; ct < 4; ++ct) {
      const int ucol = wc4 * 64 + ct * 16 + li;
      const float b1v = b1f[f0 + ucol];
#pragma unroll
      for (int r = 0; r < 4; ++r) {
        float g = gelu(uacc[ct][r] + b1v);
        float go = __shfl_xor(g, 1, 64);
        if (!(l & 1)) {
          const int row = rt * 16 + lg * 4 + r;
          *(unsigned*)(GB + row * 528 + (wc4 * 64 + ct * 16 + (li & 14)) * 2) = pack2(g, go);
        }
      }
    }
    __syncthreads();
    f16x8 wv2[4]; float4 fv[8];
    const int w2fi = t & 31, w2hg = t >> 5;
    if (WS) {
#pragma unroll
      for (int q = 0; q < 4; ++q)
        wv2[q] = *(const f16x8*)(w2t + (size_t)t * FFD + f0 + q * 8);
    } else {
#pragma unroll
      for (int q = 0; q < 8; ++q)
        fv[q] = ld4(w2 + (size_t)(f0 + w2fi) * HH + w2hg * 32 + q * 4);
    }
    for (int fc = 0; fc < 8; ++fc) {
      if (WS) {
#pragma unroll
        for (int q = 0; q < 4; ++q) *(f16x8*)(W2B + t * 80 + q * 16) = wv2[q];
      } else {
#pragma unroll
        for (int q = 0; q < 8; ++q) {
          float vv[4] = {fv[q].x, fv[q].y, fv[q].z, fv[q].w};
#pragma unroll
          for (int i = 0; i < 4; ++i)
            *(ushort*)(W2B + (w2hg * 32 + q * 4 + i) * 80 + w2fi * 2) = h2u((f16)vv[i]);
        }
      }
      if (fc < 7) {
        const int fk = f0 + (fc + 1) * 32;
        if (WS) {
#pragma unroll
          for (int q = 0; q < 4; ++q)
            wv2[q] = *(const f16x8*)(w2t + (size_t)t * FFD + fk + q * 8);
        } else {
#pragma unroll
          for (int q = 0; q < 8; ++q)
            fv[q] = ld4(w2 + (size_t)(fk + w2fi) * HH + w2hg * 32 + q * 4);
        }
      }
      __syncthreads();
      f16x8 ag = *(const f16x8*)(GB + (rt * 16 + li) * 528 + fc * 64 + lg * 16);
#pragma unroll
      for (int ti = 0; ti < 16; ++ti) {
        const int h = wc4 * 256 + ti * 16 + li;
        f16x8 bg = *(const f16x8*)(W2B + h * 80 + lg * 16);
        Oacc[ti] = MFMA16(ag, bg, Oacc[ti]);
      }
      __syncthreads();
    }
  }

  const float4 dummy = {0,0,0,0}; (void)dummy;
  float musum[4] = {0.f, 0.f, 0.f, 0.f};
#pragma unroll
  for (int ti = 0; ti < 16; ++ti) {
    const int col = wc4 * 256 + ti * 16 + li;
    const float b2v = b2f[col];
#pragma unroll
    for (int r = 0; r < 4; ++r) {
      const int row = rt * 16 + lg * 4 + r;
      float v = hb[(size_t)row * HH + col] + Oacc[ti][r] + b2v;
      Oacc[ti][r] = v; musum[r] += v;
    }
  }
#pragma unroll
  for (int off = 1; off <= 8; off <<= 1)
#pragma unroll
    for (int r = 0; r < 4; ++r) musum[r] += __shfl_xor(musum[r], off, 64);
  if (li == 0)
#pragma unroll
    for (int r = 0; r < 4; ++r) RD[wc4 * 64 + rt * 16 + lg * 4 + r] = musum[r];
  __syncthreads();
  float mu[4];
#pragma unroll
  for (int r = 0; r < 4; ++r) {
    const int row = rt * 16 + lg * 4 + r;
    float s = 0.f;
#pragma unroll
    for (int w2i = 0; w2i < 4; ++w2i) s += RD[w2i * 64 + row];
    mu[r] = s * (1.0f / HH);
  }
  float vsum[4] = {0.f, 0.f, 0.f, 0.f};
#pragma unroll
  for (int ti = 0; ti < 16; ++ti)
#pragma unroll
    for (int r = 0; r < 4; ++r) { float d = Oacc[ti][r] - mu[r]; vsum[r] += d * d; }
#pragma unroll
  for (int off = 1; off <= 8; off <<= 1)
#pragma unroll
    for (int r = 0; r < 4; ++r) vsum[r] += __shfl_xor(vsum[r], off, 64);
  if (li == 0)
#pragma unroll
    for (int r = 0; r < 4; ++r) RD2[wc4 * 64 + rt * 16 + lg * 4 + r] = vsum[r];
  __syncthreads();
  float rs[4];
#pragma unroll
  for (int r = 0; r < 4; ++r) {
    const int row = rt * 16 + lg * 4 + r;
    float s = 0.f;
#pragma unroll
    for (int w2i = 0; w2i < 4; ++w2i) s += RD2[w2i * 64 + row];
    rs[r] = rsqrtf(s * (1.0f / HH) + EPS_);
  }
#pragma unroll
  for (int ti = 0; ti < 16; ++ti) {
    const int col = wc4 * 256 + ti * 16 + li;
    const float gv = g2[col], bv = lb2[col];
#pragma unroll
    for (int r = 0; r < 4; ++r) {
      const int row = rt * 16 + lg * 4 + r;
      hb[(size_t)row * HH + col] = (Oacc[ti][r] - mu[r]) * rs[r] * gv + bv;
    }
  }
}

extern "C" void kernel_launch(void* const* d_in, const int* in_sizes, int n_in,
                              void* d_out, int out_size, void* d_ws, size_t ws_size,
                              hipStream_t stream) {
  (void)in_sizes; (void)n_in; (void)out_size;
  const float* x    = (const float*)d_in[0];
  const float* ln1g = (const float*)d_in[1];
  const float* ln1b = (const float*)d_in[2];
  const float* ln2g = (const float*)d_in[3];
  const float* ln2b = (const float*)d_in[4];
  const float* w1   = (const float*)d_in[5];
  const float* bb1  = (const float*)d_in[6];
  const float* w2   = (const float*)d_in[7];
  const float* bb2  = (const float*)d_in[8];
  float* out = (float*)d_out;

  const size_t wN   = (size_t)FFD * HH;          // 4M f16 per weight
  const size_t xN   = (size_t)NB * NN * HH;      // 16M f16 per x-copy
  const size_t need_w    = 2 * wN * sizeof(f16);               // 16 MiB
  const size_t need_full = need_w + 3 * xN * sizeof(f16);      // 112 MiB
  const bool ws_w    = (ws_size >= need_w) && d_ws;
  const bool ws_full = (ws_size >= need_full) && d_ws;

  f16* w1t = (f16*)d_ws;
  f16* w2t = w1t + wN;
  f16* xh  = w2t + wN;
  f16* xl  = xh + xN;
  f16* xt  = xl + xN;

  (void)hipFuncSetAttribute((const void*)attn_v2,
                            hipFuncAttributeMaxDynamicSharedMemorySize, 101376);
  (void)hipFuncSetAttribute((const void*)attn_legacy,
                            hipFuncAttributeMaxDynamicSharedMemorySize, 146944);
  (void)hipFuncSetAttribute((const void*)ffn_kernel<true>,
                            hipFuncAttributeMaxDynamicSharedMemorySize, 143360);
  (void)hipFuncSetAttribute((const void*)ffn_kernel<false>,
                            hipFuncAttributeMaxDynamicSharedMemorySize, 143360);

  if (ws_w) {
    transpose_f16k<<<dim3(FFD / 32, HH / 32, 1), 256, 0, stream>>>(w1, w1t, HH, FFD, 0, 0);
    transpose_f16k<<<dim3(HH / 32, FFD / 32, 1), 256, 0, stream>>>(w2, w2t, FFD, HH, 0, 0);
  }
  if (ws_full) {
    convert_hl<<<(int)(xN / 4 / 256), 256, 0, stream>>>(x, xh, xl);
    transpose_f16k<<<dim3(HH / 32, NN / 32, NB), 256, 0, stream>>>(
        x, xt, NN, HH, (long)NN * HH, (long)HH * NN);
    attn_v2<<<dim3(NN / 64, NB), 512, 101376, stream>>>(x, xh, xl, xt, ln1g, ln1b, out);
  } else {
    attn_legacy<<<dim3(NN / 32, NB), 1024, 146944, stream>>>(x, ln1g, ln1b, out);
  }
  if (ws_w)
    ffn_kernel<true><<<dim3(NN / 64, NB), 1024, 143360, stream>>>(
        out, ln2g, ln2b, w1, bb1, w2, bb2, w1t, w2t);
  else
    ffn_kernel<false><<<dim3(NN / 64, NB), 1024, 143360, stream>>>(
        out, ln2g, ln2b, w1, bb1, w2, bb2, nullptr, nullptr);
}